// Round 5
// baseline (1012.631 us; speedup 1.0000x reference)
//
#include <hip/hip_runtime.h>
#include <hip/hip_fp16.h>

#define CC 256
#define HWIMG 4096
#define NPIX 131072
#define KCODES 1024
#define PAIRCAP 65536
#define FULLCAP 8192
#define MARGIN 0.125f

typedef _Float16 half8 __attribute__((ext_vector_type(8)));
typedef short short8v __attribute__((ext_vector_type(8)));
typedef float f32x4 __attribute__((ext_vector_type(4)));
typedef unsigned short u16;
typedef unsigned int u32;

__device__ __forceinline__ void gld16(const void* g, void* l) {
    __builtin_amdgcn_global_load_lds(
        (const __attribute__((address_space(1))) void*)g,
        (__attribute__((address_space(3))) void*)l, 16, 0, 0);
}

// merge sorted triple (m1,i1,m2,i2,m3) with (bm1,bi1,bm2,bi2,bm3)
__device__ __forceinline__ void merge3(
    float& m1, int& i1, float& m2, int& i2, float& m3,
    float bm1, int bi1, float bm2, int bi2, float bm3)
{
    if (bm1 < m1 || (bm1 == m1 && bi1 < i1)) {
        float t; int ti;
        t = m1; m1 = bm1; bm1 = t;  ti = i1; i1 = bi1; bi1 = ti;
        t = m2; m2 = bm2; bm2 = t;  ti = i2; i2 = bi2; bi2 = ti;
        t = m3; m3 = bm3; bm3 = t;
    }
    if (bm1 < m2 || (bm1 == m2 && bi1 < i2)) {
        m3 = fminf(m2, bm2);
        m2 = bm1; i2 = bi1;
    } else {
        m3 = fminf(m3, bm1);
    }
}

// ---------- prep_e: codebook -> fp16 pre-swizzled chunk images + esq ---------
__global__ __launch_bounds__(256) void prep_e(const float* __restrict__ cb,
    u16* __restrict__ e_prep, float* __restrict__ esq, int* __restrict__ cnts)
{
    __shared__ u16 eh[256];
    __shared__ float red[4];
    int k = blockIdx.x, c = threadIdx.x;
    float v = cb[(size_t)k * CC + c];
    eh[c] = __half_as_ushort(__float2half(v));
    float s = v * v;
    #pragma unroll
    for (int m = 32; m; m >>= 1) s += __shfl_xor(s, m, 64);
    if ((c & 63) == 0) red[c >> 6] = s;
    __syncthreads();
    if (c == 0) {
        esq[k] = (red[0] + red[1]) + (red[2] + red[3]);
        if (k == 0) { cnts[0] = 0; cnts[1] = 0; }
    }
    if (c < 32) {
        int ks = c >> 3, cg = c & 7;
        int pass = k >> 8, row = k & 255;
        int o = (row * 128 + cg * 16) ^ ((row & 7) << 4);
        short8v w;
        #pragma unroll
        for (int j = 0; j < 8; ++j) w[j] = (short)eh[ks * 64 + cg * 8 + j];
        *(short8v*)((char*)e_prep + (size_t)(pass * 4 + ks) * 32768 + o) = w;
    }
}

// ---------- prep_xT: x NCHW fp32 -> fp16 hi/lo pre-swizzled chunks (d_out) ---
__global__ __launch_bounds__(256) void prep_xT(const float* __restrict__ x,
    char* __restrict__ x_prep)
{
    __shared__ u32 pk[64 * 260];
    const int blk = blockIdx.x, t = threadIdx.x;
    const float* xb = x + (size_t)(blk >> 6) * (CC * HWIMG) + (blk & 63) * 64;
    #pragma unroll 4
    for (int p = 0; p < 16; ++p) {
        int c = p * 16 + (t >> 4);
        int px4 = (t & 15) * 4;
        float4 v = *(const float4*)&xb[(size_t)c * HWIMG + px4];
        float vv[4] = {v.x, v.y, v.z, v.w};
        #pragma unroll
        for (int i = 0; i < 4; ++i) {
            __half h = __float2half(vv[i]);
            __half lo = __float2half(vv[i] - __half2float(h));
            pk[(px4 + i) * 260 + c] =
                ((u32)__half_as_ushort(h) << 16) | __half_as_ushort(lo);
        }
    }
    __syncthreads();
    char* obase = x_prep + (size_t)blk * 65536;
    #pragma unroll
    for (int i = 0; i < 16; ++i) {
        int gid = t + 256 * i;            // [ks 4][h 2][g 512]
        int ks = gid >> 10, rem = gid & 1023, h = rem >> 9, g = rem & 511;
        int row = g >> 3;
        int cg = (g & 7) ^ (row & 7);
        int c0 = ks * 64 + cg * 8;
        const u32* pr = &pk[row * 260 + c0];
        uint4 a = *(const uint4*)pr;
        uint4 b = *(const uint4*)(pr + 4);
        u32 w[8] = {a.x, a.y, a.z, a.w, b.x, b.y, b.z, b.w};
        short8v ov;
        #pragma unroll
        for (int j = 0; j < 8; ++j)
            ov[j] = h ? (short)(w[j] & 0xFFFF) : (short)(w[j] >> 16);
        *(short8v*)(obase + (size_t)ks * 16384 + h * 8192 + g * 16) = ov;
    }
}

// ---------- dist: 2-term fp16 MFMA distance + top-3 argmin -------------------
__global__ __launch_bounds__(256, 3) void dist_kernel(
    const char* __restrict__ x_prep, const char* __restrict__ e_prep,
    const float* __restrict__ esq,
    int* __restrict__ min_idx, int* __restrict__ cnts,
    int2* __restrict__ pair_list, int* __restrict__ full_list)
{
    __shared__ char smem[49152];
    char* xhp = smem;
    char* xlp = smem + 8192;
    char* ehp = smem + 16384;

    const int t = threadIdx.x;
    const int l = t & 63;
    const int wid = t >> 6;
    const int n0 = blockIdx.x * 64;

    const int lrow = l & 15;
    const int lk   = (l >> 4) * 16;
    const int lx   = (l & 7) << 4;

    const char* xsrc = x_prep + (size_t)blockIdx.x * 65536;

    float min1[16], min2[16], min3[16]; int idx1[16], idx2[16];
    #pragma unroll
    for (int s = 0; s < 16; ++s) {
        min1[s] = 3.4e38f; min2[s] = 3.4e38f; min3[s] = 3.4e38f;
        idx1[s] = 0; idx2[s] = 0;
    }

    f32x4 acc[4][4];

    for (int r = 0; r < 16; ++r) {
        const int pass = r >> 2, ks = r & 3;
        {
            const char* xs = xsrc + ks * 16384;
            const char* es = e_prep + r * 32768;
            #pragma unroll
            for (int i = 0; i < 4; ++i)
                gld16(xs + wid * 4096 + i * 1024 + l * 16,
                      smem + wid * 4096 + i * 1024);
            #pragma unroll
            for (int i = 0; i < 8; ++i)
                gld16(es + wid * 8192 + i * 1024 + l * 16,
                      ehp + wid * 8192 + i * 1024);
        }
        asm volatile("s_waitcnt vmcnt(0)" ::: "memory");
        __syncthreads();

        if (ks == 0) {
            #pragma unroll
            for (int m = 0; m < 4; ++m)
                #pragma unroll
                for (int n = 0; n < 4; ++n) acc[m][n] = (f32x4){0.f, 0.f, 0.f, 0.f};
        }
        #pragma unroll
        for (int sub = 0; sub < 2; ++sub) {
            half8 B[4];
            #pragma unroll
            for (int n = 0; n < 4; ++n) {
                int raw = (wid * 64 + n * 16 + lrow) * 128 + sub * 64 + lk;
                B[n] = *(const half8*)(ehp + (raw ^ lx));
            }
            #pragma unroll
            for (int m = 0; m < 4; ++m) {
                int raw = (m * 16 + lrow) * 128 + sub * 64 + lk;
                half8 Ah = *(const half8*)(xhp + (raw ^ lx));
                half8 Al = *(const half8*)(xlp + (raw ^ lx));
                #pragma unroll
                for (int n = 0; n < 4; ++n) {
                    acc[m][n] = __builtin_amdgcn_mfma_f32_16x16x32_f16(Ah, B[n], acc[m][n], 0, 0, 0);
                    acc[m][n] = __builtin_amdgcn_mfma_f32_16x16x32_f16(Al, B[n], acc[m][n], 0, 0, 0);
                }
            }
        }
        if (ks == 3) {   // pass epilogue: d = esq - 2*dot, top-3 update
            #pragma unroll
            for (int n = 0; n < 4; ++n) {
                int code = pass * 256 + wid * 64 + n * 16 + lrow;
                float eq = esq[code];
                #pragma unroll
                for (int m = 0; m < 4; ++m) {
                    #pragma unroll
                    for (int q = 0; q < 4; ++q) {
                        float d = fmaf(-2.0f, acc[m][n][q], eq);
                        int s = m * 4 + q;
                        if (d < min1[s]) {
                            min3[s] = min2[s]; min2[s] = min1[s]; idx2[s] = idx1[s];
                            min1[s] = d; idx1[s] = code;
                        } else if (d < min2[s]) {
                            min3[s] = min2[s]; min2[s] = d; idx2[s] = code;
                        } else if (d < min3[s]) {
                            min3[s] = d;
                        }
                    }
                }
            }
        }
        __syncthreads();
    }

    // reduce across 16 code-lanes (lrow), then across the 4 waves
    float* rm1 = (float*)smem;
    float* rm2 = (float*)(smem + 1024);
    float* rm3 = (float*)(smem + 2048);
    int*   ri1 = (int*)(smem + 3072);
    int*   ri2 = (int*)(smem + 4096);
    #pragma unroll
    for (int s = 0; s < 16; ++s) {
        float m1 = min1[s], m2 = min2[s], m3 = min3[s];
        int i1 = idx1[s], i2 = idx2[s];
        #pragma unroll
        for (int msk = 1; msk <= 8; msk <<= 1) {
            float o1 = __shfl_xor(m1, msk, 64);
            float o2 = __shfl_xor(m2, msk, 64);
            float o3 = __shfl_xor(m3, msk, 64);
            int   a1 = __shfl_xor(i1, msk, 64);
            int   a2 = __shfl_xor(i2, msk, 64);
            merge3(m1, i1, m2, i2, m3, o1, a1, o2, a2, o3);
        }
        if (lrow == 0) {
            int px_local = (s >> 2) * 16 + (l >> 4) * 4 + (s & 3);
            rm1[wid * 64 + px_local] = m1;
            rm2[wid * 64 + px_local] = m2;
            rm3[wid * 64 + px_local] = m3;
            ri1[wid * 64 + px_local] = i1;
            ri2[wid * 64 + px_local] = i2;
        }
    }
    __syncthreads();
    if (t < 64) {
        float m1 = rm1[t], m2 = rm2[t], m3 = rm3[t];
        int i1 = ri1[t], i2 = ri2[t];
        #pragma unroll
        for (int w = 1; w < 4; ++w) {
            merge3(m1, i1, m2, i2, m3,
                   rm1[w * 64 + t], ri1[w * 64 + t],
                   rm2[w * 64 + t], ri2[w * 64 + t], rm3[w * 64 + t]);
        }
        int n = n0 + t;
        min_idx[n] = i1;
        if (m3 - m1 <= MARGIN) {            // >=3 candidates: full fp64 sweep
            int slot = atomicAdd(&cnts[1], 1);
            if (slot < FULLCAP) full_list[slot] = n;
        } else if (m2 - m1 <= MARGIN) {     // 2 candidates: fp64 pair compare
            int slot = atomicAdd(&cnts[0], 1);
            if (slot < PAIRCAP) pair_list[slot] = make_int2(n, (i1 << 16) | i2);
        }
    }
}

// ---------- recheck_pair: fp64 compare of the two candidates (1 wave/px) -----
__global__ __launch_bounds__(256) void recheck_pair(
    const float* __restrict__ x, const float* __restrict__ cb,
    const int* __restrict__ cnts, const int2* __restrict__ pair_list,
    int* __restrict__ min_idx)
{
    int cnt = cnts[0]; if (cnt > PAIRCAP) cnt = PAIRCAP;
    const int l = threadIdx.x & 63;
    const int wslot = blockIdx.x * 4 + (threadIdx.x >> 6);
    for (int f = wslot; f < cnt; f += gridDim.x * 4) {
        int2 pr = pair_list[f];
        int n = pr.x, i1 = pr.y >> 16, i2 = pr.y & 0xFFFF;
        int b = n / HWIMG, hw = n % HWIMG;
        const float* xb = x + (size_t)b * CC * HWIMG + hw;
        float4 e1 = *(const float4*)&cb[(size_t)i1 * CC + l * 4];
        float4 e2 = *(const float4*)&cb[(size_t)i2 * CC + l * 4];
        float xv[4];
        #pragma unroll
        for (int j = 0; j < 4; ++j) xv[j] = xb[(size_t)(l * 4 + j) * HWIMG];
        float e1a[4] = {e1.x, e1.y, e1.z, e1.w};
        float e2a[4] = {e2.x, e2.y, e2.z, e2.w};
        double s1 = 0.0, s2 = 0.0;
        #pragma unroll
        for (int j = 0; j < 4; ++j) {
            double xd = (double)xv[j];
            double d1 = xd - (double)e1a[j];
            double d2 = xd - (double)e2a[j];
            s1 = fma(d1, d1, s1);
            s2 = fma(d2, d2, s2);
        }
        #pragma unroll
        for (int m = 32; m; m >>= 1) {
            s1 += __shfl_xor(s1, m, 64);
            s2 += __shfl_xor(s2, m, 64);
        }
        if (l == 0) {
            int best = (s2 < s1 || (s2 == s1 && i2 < i1)) ? i2 : i1;
            min_idx[n] = best;
        }
    }
}

// ---------- recheck_full: fp64 exact argmin over all codes (rare) ------------
__global__ __launch_bounds__(256) void recheck_full(
    const float* __restrict__ x, const float* __restrict__ cb,
    const int* __restrict__ cnts, const int* __restrict__ full_list,
    int* __restrict__ min_idx)
{
    __shared__ float xv[CC];
    __shared__ double rv[256];
    __shared__ int    ri[256];
    int cnt = cnts[1]; if (cnt > FULLCAP) cnt = FULLCAP;
    for (int f = blockIdx.x; f < cnt; f += gridDim.x) {
        int n = full_list[f];
        int b = n / HWIMG, hw = n % HWIMG;
        const float* xb = x + (size_t)b * CC * HWIMG + hw;
        for (int c = threadIdx.x; c < CC; c += 256) xv[c] = xb[(size_t)c * HWIMG];
        __syncthreads();
        double best = 1e300; int bidx = KCODES;
        #pragma unroll
        for (int kk = 0; kk < 4; kk++) {
            int k = threadIdx.x * 4 + kk;
            const float* er = cb + (size_t)k * CC;
            double s = 0.0;
            #pragma unroll 4
            for (int c = 0; c < CC; c++) {
                double diff = (double)xv[c] - (double)er[c];
                s = fma(diff, diff, s);
            }
            if (s < best) { best = s; bidx = k; }
        }
        rv[threadIdx.x] = best; ri[threadIdx.x] = bidx;
        __syncthreads();
        for (int s2 = 128; s2; s2 >>= 1) {
            if (threadIdx.x < (unsigned)s2) {
                double ov = rv[threadIdx.x + s2]; int oi = ri[threadIdx.x + s2];
                if (ov < rv[threadIdx.x] ||
                    (ov == rv[threadIdx.x] && oi < ri[threadIdx.x])) {
                    rv[threadIdx.x] = ov; ri[threadIdx.x] = oi;
                }
            }
            __syncthreads();
        }
        if (threadIdx.x == 0) min_idx[n] = ri[0];
        __syncthreads();
    }
}

// ---------- out: gather quantized (NCHW) + fp64 loss partials ----------------
__global__ __launch_bounds__(256) void out_kernel(
    const float* __restrict__ x, const float* __restrict__ cb,
    const int* __restrict__ min_idx, float* __restrict__ out,
    double* __restrict__ partials)
{
    int n = blockIdx.x * 256 + threadIdx.x;
    int b = n / HWIMG, hw = n % HWIMG;
    const float* xb = x + (size_t)b * CC * HWIMG + hw;
    float*       ob = out + (size_t)b * CC * HWIMG + hw;
    int k = min_idx[n];
    const float* er = cb + (size_t)k * CC;
    double ls = 0.0;
    #pragma unroll 4
    for (int c = 0; c < CC; c += 4) {
        float4 q = *(const float4*)&er[c];
        float x0 = xb[(size_t)(c + 0) * HWIMG];
        float x1 = xb[(size_t)(c + 1) * HWIMG];
        float x2 = xb[(size_t)(c + 2) * HWIMG];
        float x3 = xb[(size_t)(c + 3) * HWIMG];
        ob[(size_t)(c + 0) * HWIMG] = q.x;
        ob[(size_t)(c + 1) * HWIMG] = q.y;
        ob[(size_t)(c + 2) * HWIMG] = q.z;
        ob[(size_t)(c + 3) * HWIMG] = q.w;
        double d0 = (double)q.x - (double)x0;
        double d1 = (double)q.y - (double)x1;
        double d2 = (double)q.z - (double)x2;
        double d3 = (double)q.w - (double)x3;
        ls += d0 * d0 + d1 * d1 + d2 * d2 + d3 * d3;
    }
    __shared__ double sred[256];
    sred[threadIdx.x] = ls;
    __syncthreads();
    for (int s = 128; s; s >>= 1) {
        if (threadIdx.x < (unsigned)s) sred[threadIdx.x] += sred[threadIdx.x + s];
        __syncthreads();
    }
    if (threadIdx.x == 0) partials[blockIdx.x] = sred[0];
}

__global__ void loss_kernel(const double* __restrict__ partials, float* __restrict__ out)
{
    if (threadIdx.x == 0 && blockIdx.x == 0) {
        double s = 0.0;
        for (int i = 0; i < 512; i++) s += partials[i];
        out[33554432] = (float)(1.25 * s / 33554432.0);
    }
}

// ---------- launch -----------------------------------------------------------
extern "C" void kernel_launch(void* const* d_in, const int* in_sizes, int n_in,
                              void* d_out, int out_size, void* d_ws, size_t ws_size,
                              hipStream_t stream)
{
    const float* x  = (const float*)d_in[0];
    const float* cb = (const float*)d_in[1];
    float* out = (float*)d_out;

    // x_prep (128 MB) lives in d_out; out_kernel rewrites d_out afterwards.
    char* x_prep = (char*)d_out;

    char* ws = (char*)d_ws;
    u16*    e_prep    = (u16*)  (ws + 0);            //   524,288 B
    float*  esq       = (float*)(ws + 524288);       //     4,096 B
    int*    min_idx   = (int*)  (ws + 528384);       //   524,288 B
    int*    cnts      = (int*)  (ws + 1052672);      //        16 B [pair, full]
    int2*   pair_list = (int2*) (ws + 1052688);      //   524,288 B
    int*    full_list = (int*)  (ws + 1576976);      //    32,768 B
    double* partials  = (double*)(ws + 1609744);     //     4,096 B

    prep_e       <<<KCODES, 256, 0, stream>>>(cb, e_prep, esq, cnts);
    prep_xT      <<<NPIX / 64, 256, 0, stream>>>(x, x_prep);
    dist_kernel  <<<NPIX / 64, 256, 0, stream>>>(x_prep, (const char*)e_prep, esq,
                                                 min_idx, cnts, pair_list, full_list);
    recheck_pair <<<512, 256, 0, stream>>>(x, cb, cnts, pair_list, min_idx);
    recheck_full <<<64, 256, 0, stream>>>(x, cb, cnts, full_list, min_idx);
    out_kernel   <<<NPIX / 256, 256, 0, stream>>>(x, cb, min_idx, out, partials);
    loss_kernel  <<<1, 64, 0, stream>>>(partials, out);
}

// Round 6
// 410.805 us; speedup vs baseline: 2.4650x; 2.4650x over previous
//
#include <hip/hip_runtime.h>
#include <hip/hip_fp16.h>

#define CC 256
#define HWIMG 4096
#define NPIX 131072
#define KCODES 1024
#define FULLCAP 32768
#define MARGIN 0.125f

typedef _Float16 half8 __attribute__((ext_vector_type(8)));
typedef short short8v __attribute__((ext_vector_type(8)));
typedef float f32x4 __attribute__((ext_vector_type(4)));
typedef unsigned short u16;
typedef unsigned int u32;

__device__ __forceinline__ void gld16(const void* g, void* l) {
    __builtin_amdgcn_global_load_lds(
        (const __attribute__((address_space(1))) void*)g,
        (__attribute__((address_space(3))) void*)l, 16, 0, 0);
}

// ---------- prep_e: codebook -> fp16 pre-swizzled chunk images + esq ---------
__global__ __launch_bounds__(256) void prep_e(const float* __restrict__ cb,
    u16* __restrict__ e_prep, float* __restrict__ esq, int* __restrict__ cnts)
{
    __shared__ u16 eh[256];
    __shared__ float red[4];
    int k = blockIdx.x, c = threadIdx.x;
    float v = cb[(size_t)k * CC + c];
    eh[c] = __half_as_ushort(__float2half(v));
    float s = v * v;
    #pragma unroll
    for (int m = 32; m; m >>= 1) s += __shfl_xor(s, m, 64);
    if ((c & 63) == 0) red[c >> 6] = s;
    __syncthreads();
    if (c == 0) {
        esq[k] = (red[0] + red[1]) + (red[2] + red[3]);
        if (k == 0) { cnts[0] = 0; cnts[1] = 0; }
    }
    if (c < 32) {
        int ks = c >> 3, cg = c & 7;
        int pass = k >> 8, row = k & 255;
        int o = (row * 128 + cg * 16) ^ ((row & 7) << 4);
        short8v w;
        #pragma unroll
        for (int j = 0; j < 8; ++j) w[j] = (short)eh[ks * 64 + cg * 8 + j];
        *(short8v*)((char*)e_prep + (size_t)(pass * 4 + ks) * 32768 + o) = w;
    }
}

// ---------- prep_xT: x NCHW fp32 -> fp16 hi/lo pre-swizzled chunks (d_out) ---
__global__ __launch_bounds__(256) void prep_xT(const float* __restrict__ x,
    char* __restrict__ x_prep)
{
    __shared__ u32 pk[64 * 260];
    const int blk = blockIdx.x, t = threadIdx.x;
    const float* xb = x + (size_t)(blk >> 6) * (CC * HWIMG) + (blk & 63) * 64;
    #pragma unroll 4
    for (int p = 0; p < 16; ++p) {
        int c = p * 16 + (t >> 4);
        int px4 = (t & 15) * 4;
        float4 v = *(const float4*)&xb[(size_t)c * HWIMG + px4];
        float vv[4] = {v.x, v.y, v.z, v.w};
        #pragma unroll
        for (int i = 0; i < 4; ++i) {
            __half h = __float2half(vv[i]);
            __half lo = __float2half(vv[i] - __half2float(h));
            pk[(px4 + i) * 260 + c] =
                ((u32)__half_as_ushort(h) << 16) | __half_as_ushort(lo);
        }
    }
    __syncthreads();
    char* obase = x_prep + (size_t)blk * 65536;
    #pragma unroll
    for (int i = 0; i < 16; ++i) {
        int gid = t + 256 * i;            // [ks 4][h 2][g 512]
        int ks = gid >> 10, rem = gid & 1023, h = rem >> 9, g = rem & 511;
        int row = g >> 3;
        int cg = (g & 7) ^ (row & 7);
        int c0 = ks * 64 + cg * 8;
        const u32* pr = &pk[row * 260 + c0];
        uint4 a = *(const uint4*)pr;
        uint4 b = *(const uint4*)(pr + 4);
        u32 w[8] = {a.x, a.y, a.z, a.w, b.x, b.y, b.z, b.w};
        short8v ov;
        #pragma unroll
        for (int j = 0; j < 8; ++j)
            ov[j] = h ? (short)(w[j] & 0xFFFF) : (short)(w[j] >> 16);
        *(short8v*)(obase + (size_t)ks * 16384 + h * 8192 + g * 16) = ov;
    }
}

// ---------- dist: 2-term fp16 MFMA distance + top-2 argmin (round-4 proven) --
__global__ __launch_bounds__(256, 3) void dist_kernel(
    const char* __restrict__ x_prep, const char* __restrict__ e_prep,
    const float* __restrict__ esq,
    int* __restrict__ min_idx, int* __restrict__ cnts,
    int* __restrict__ full_list)
{
    __shared__ char smem[49152];
    char* xhp = smem;
    char* xlp = smem + 8192;
    char* ehp = smem + 16384;

    const int t = threadIdx.x;
    const int l = t & 63;
    const int wid = t >> 6;
    const int n0 = blockIdx.x * 64;

    const int lrow = l & 15;
    const int lk   = (l >> 4) * 16;
    const int lx   = (l & 7) << 4;

    const char* xsrc = x_prep + (size_t)blockIdx.x * 65536;

    float min1[16], min2[16]; int idx1[16];
    #pragma unroll
    for (int s = 0; s < 16; ++s) { min1[s] = 3.4e38f; min2[s] = 3.4e38f; idx1[s] = 0; }

    f32x4 acc[4][4];

    for (int r = 0; r < 16; ++r) {
        const int pass = r >> 2, ks = r & 3;
        {
            const char* xs = xsrc + ks * 16384;
            const char* es = e_prep + r * 32768;
            #pragma unroll
            for (int i = 0; i < 4; ++i)
                gld16(xs + wid * 4096 + i * 1024 + l * 16,
                      smem + wid * 4096 + i * 1024);
            #pragma unroll
            for (int i = 0; i < 8; ++i)
                gld16(es + wid * 8192 + i * 1024 + l * 16,
                      ehp + wid * 8192 + i * 1024);
        }
        asm volatile("s_waitcnt vmcnt(0)" ::: "memory");
        __syncthreads();

        if (ks == 0) {
            #pragma unroll
            for (int m = 0; m < 4; ++m)
                #pragma unroll
                for (int n = 0; n < 4; ++n) acc[m][n] = (f32x4){0.f, 0.f, 0.f, 0.f};
        }
        #pragma unroll
        for (int sub = 0; sub < 2; ++sub) {
            half8 B[4];
            #pragma unroll
            for (int n = 0; n < 4; ++n) {
                int raw = (wid * 64 + n * 16 + lrow) * 128 + sub * 64 + lk;
                B[n] = *(const half8*)(ehp + (raw ^ lx));
            }
            #pragma unroll
            for (int m = 0; m < 4; ++m) {
                int raw = (m * 16 + lrow) * 128 + sub * 64 + lk;
                half8 Ah = *(const half8*)(xhp + (raw ^ lx));
                half8 Al = *(const half8*)(xlp + (raw ^ lx));
                #pragma unroll
                for (int n = 0; n < 4; ++n) {
                    acc[m][n] = __builtin_amdgcn_mfma_f32_16x16x32_f16(Ah, B[n], acc[m][n], 0, 0, 0);
                    acc[m][n] = __builtin_amdgcn_mfma_f32_16x16x32_f16(Al, B[n], acc[m][n], 0, 0, 0);
                }
            }
        }
        if (ks == 3) {   // pass epilogue: d = esq - 2*dot, top-2 update
            #pragma unroll
            for (int n = 0; n < 4; ++n) {
                int code = pass * 256 + wid * 64 + n * 16 + lrow;
                float eq = esq[code];
                #pragma unroll
                for (int m = 0; m < 4; ++m) {
                    #pragma unroll
                    for (int q = 0; q < 4; ++q) {
                        float d = fmaf(-2.0f, acc[m][n][q], eq);
                        int s = m * 4 + q;
                        if (d < min1[s]) { min2[s] = min1[s]; min1[s] = d; idx1[s] = code; }
                        else if (d < min2[s]) { min2[s] = d; }
                    }
                }
            }
        }
        __syncthreads();
    }

    // reduce across 16 code-lanes, then across the 4 waves
    float* rm1 = (float*)smem;
    float* rm2 = (float*)(smem + 1024);
    int*   rim = (int*)(smem + 2048);
    #pragma unroll
    for (int s = 0; s < 16; ++s) {
        float m1 = min1[s]; int i1 = idx1[s]; float m2 = min2[s];
        #pragma unroll
        for (int msk = 1; msk <= 8; msk <<= 1) {
            float o1 = __shfl_xor(m1, msk, 64);
            int   oi = __shfl_xor(i1, msk, 64);
            float o2 = __shfl_xor(m2, msk, 64);
            if (o1 < m1 || (o1 == m1 && oi < i1)) { m2 = fminf(fminf(m2, o2), m1); m1 = o1; i1 = oi; }
            else { m2 = fminf(fminf(m2, o2), o1); }
        }
        if (lrow == 0) {
            int px_local = (s >> 2) * 16 + (l >> 4) * 4 + (s & 3);
            rm1[wid * 64 + px_local] = m1;
            rm2[wid * 64 + px_local] = m2;
            rim[wid * 64 + px_local] = i1;
        }
    }
    __syncthreads();
    if (t < 64) {
        float m1 = rm1[t]; int i1 = rim[t]; float m2 = rm2[t];
        #pragma unroll
        for (int w = 1; w < 4; ++w) {
            float o1 = rm1[w * 64 + t]; int oi = rim[w * 64 + t]; float o2 = rm2[w * 64 + t];
            if (o1 < m1 || (o1 == m1 && oi < i1)) { m2 = fminf(fminf(m2, o2), m1); m1 = o1; i1 = oi; }
            else { m2 = fminf(fminf(m2, o2), o1); }
        }
        int n = n0 + t;
        min_idx[n] = i1;
        if (m2 - m1 <= MARGIN) {
            int slot = atomicAdd(&cnts[0], 1);
            if (slot < FULLCAP) full_list[slot] = n;
        }
    }
}

// ---------- recheck_full4: fp64 exact argmin, 4 flagged pixels per block -----
// 256 thr, 4 codes/thread, 16 interleaved fp64 chains, x rows broadcast in LDS.
__global__ __launch_bounds__(256) void recheck_full4(
    const float* __restrict__ x, const float* __restrict__ cb,
    const int* __restrict__ cnts, const int* __restrict__ full_list,
    int* __restrict__ min_idx)
{
    __shared__ float  xs[4][CC];       // 4 KB
    __shared__ double rbest[4][256];   // 8 KB
    __shared__ int    ribst[4][256];   // 4 KB
    int cnt = cnts[0]; if (cnt > FULLCAP) cnt = FULLCAP;
    int ngrp = (cnt + 3) >> 2;
    const int t = threadIdx.x;
    for (int g = blockIdx.x; g < ngrp; g += gridDim.x) {
        int npx = cnt - g * 4; if (npx > 4) npx = 4;
        for (int i = t; i < npx * 256; i += 256) {
            int p = i >> 8, c = i & 255;
            int n = full_list[g * 4 + p];
            int b = n / HWIMG, hw = n % HWIMG;
            xs[p][c] = x[(size_t)b * CC * HWIMG + (size_t)c * HWIMG + hw];
        }
        __syncthreads();
        double best[4] = {1e300, 1e300, 1e300, 1e300};
        int bi[4] = {0, 0, 0, 0};
        #pragma unroll
        for (int kk = 0; kk < 4; ++kk) {
            int k = t * 4 + kk;
            const float4* er = (const float4*)(cb + (size_t)k * CC);
            double s[4] = {0.0, 0.0, 0.0, 0.0};
            for (int c4 = 0; c4 < 64; ++c4) {
                float4 e = er[c4];
                float ea[4] = {e.x, e.y, e.z, e.w};
                #pragma unroll
                for (int j = 0; j < 4; ++j) {
                    #pragma unroll
                    for (int p = 0; p < 4; ++p) {
                        double d = (double)xs[p][c4 * 4 + j] - (double)ea[j];
                        s[p] = fma(d, d, s[p]);
                    }
                }
            }
            #pragma unroll
            for (int p = 0; p < 4; ++p)
                if (s[p] < best[p]) { best[p] = s[p]; bi[p] = k; }
        }
        #pragma unroll
        for (int p = 0; p < 4; ++p) { rbest[p][t] = best[p]; ribst[p][t] = bi[p]; }
        __syncthreads();
        for (int st = 128; st; st >>= 1) {
            if (t < st) {
                #pragma unroll
                for (int p = 0; p < 4; ++p) {
                    double ov = rbest[p][t + st]; int oi = ribst[p][t + st];
                    if (ov < rbest[p][t] || (ov == rbest[p][t] && oi < ribst[p][t])) {
                        rbest[p][t] = ov; ribst[p][t] = oi;
                    }
                }
            }
            __syncthreads();
        }
        if (t < npx) min_idx[full_list[g * 4 + t]] = ribst[t][0];
        __syncthreads();
    }
}

// ---------- out: gather quantized (NCHW) + fp64 loss partials ----------------
__global__ __launch_bounds__(256) void out_kernel(
    const float* __restrict__ x, const float* __restrict__ cb,
    const int* __restrict__ min_idx, float* __restrict__ out,
    double* __restrict__ partials)
{
    int n = blockIdx.x * 256 + threadIdx.x;
    int b = n / HWIMG, hw = n % HWIMG;
    const float* xb = x + (size_t)b * CC * HWIMG + hw;
    float*       ob = out + (size_t)b * CC * HWIMG + hw;
    int k = min_idx[n];
    const float* er = cb + (size_t)k * CC;
    double ls = 0.0;
    #pragma unroll 4
    for (int c = 0; c < CC; c += 4) {
        float4 q = *(const float4*)&er[c];
        float x0 = xb[(size_t)(c + 0) * HWIMG];
        float x1 = xb[(size_t)(c + 1) * HWIMG];
        float x2 = xb[(size_t)(c + 2) * HWIMG];
        float x3 = xb[(size_t)(c + 3) * HWIMG];
        ob[(size_t)(c + 0) * HWIMG] = q.x;
        ob[(size_t)(c + 1) * HWIMG] = q.y;
        ob[(size_t)(c + 2) * HWIMG] = q.z;
        ob[(size_t)(c + 3) * HWIMG] = q.w;
        double d0 = (double)q.x - (double)x0;
        double d1 = (double)q.y - (double)x1;
        double d2 = (double)q.z - (double)x2;
        double d3 = (double)q.w - (double)x3;
        ls += d0 * d0 + d1 * d1 + d2 * d2 + d3 * d3;
    }
    __shared__ double sred[256];
    sred[threadIdx.x] = ls;
    __syncthreads();
    for (int s = 128; s; s >>= 1) {
        if (threadIdx.x < (unsigned)s) sred[threadIdx.x] += sred[threadIdx.x + s];
        __syncthreads();
    }
    if (threadIdx.x == 0) partials[blockIdx.x] = sred[0];
}

__global__ void loss_kernel(const double* __restrict__ partials, float* __restrict__ out)
{
    if (threadIdx.x == 0 && blockIdx.x == 0) {
        double s = 0.0;
        for (int i = 0; i < 512; i++) s += partials[i];
        out[33554432] = (float)(1.25 * s / 33554432.0);
    }
}

// ---------- launch -----------------------------------------------------------
extern "C" void kernel_launch(void* const* d_in, const int* in_sizes, int n_in,
                              void* d_out, int out_size, void* d_ws, size_t ws_size,
                              hipStream_t stream)
{
    const float* x  = (const float*)d_in[0];
    const float* cb = (const float*)d_in[1];
    float* out = (float*)d_out;

    // x_prep (128 MB) lives in d_out; out_kernel rewrites d_out afterwards.
    char* x_prep = (char*)d_out;

    char* ws = (char*)d_ws;
    u16*    e_prep    = (u16*)  (ws + 0);            //   524,288 B
    float*  esq       = (float*)(ws + 524288);       //     4,096 B
    int*    min_idx   = (int*)  (ws + 528384);       //   524,288 B
    int*    cnts      = (int*)  (ws + 1052672);      //        16 B
    int*    full_list = (int*)  (ws + 1052688);      //   131,072 B
    double* partials  = (double*)(ws + 1183760);     //     4,096 B

    prep_e       <<<KCODES, 256, 0, stream>>>(cb, e_prep, esq, cnts);
    prep_xT      <<<NPIX / 64, 256, 0, stream>>>(x, x_prep);
    dist_kernel  <<<NPIX / 64, 256, 0, stream>>>(x_prep, (const char*)e_prep, esq,
                                                 min_idx, cnts, full_list);
    recheck_full4<<<1024, 256, 0, stream>>>(x, cb, cnts, full_list, min_idx);
    out_kernel   <<<NPIX / 256, 256, 0, stream>>>(x, cb, min_idx, out, partials);
    loss_kernel  <<<1, 64, 0, stream>>>(partials, out);
}

// Round 8
// 363.870 us; speedup vs baseline: 2.7829x; 1.1290x over previous
//
#include <hip/hip_runtime.h>
#include <hip/hip_fp16.h>

#define CC 256
#define HWIMG 4096
#define NPIX 131072
#define KCODES 1024
#define FULLCAP 32768
#define MARGIN 0.125f

typedef _Float16 half8 __attribute__((ext_vector_type(8)));
typedef short short8v __attribute__((ext_vector_type(8)));
typedef float f32x4 __attribute__((ext_vector_type(4)));
typedef unsigned short u16;
typedef unsigned int u32;

__device__ __forceinline__ void gld16(const void* g, void* l) {
    __builtin_amdgcn_global_load_lds(
        (const __attribute__((address_space(1))) void*)g,
        (__attribute__((address_space(3))) void*)l, 16, 0, 0);
}

// swizzle: 64B rows, 4x16B slots; physical slot = kg ^ ((row ^ row>>2) & 3)

// ---------- prep_e: codebook -> fp16 chunk images [32][256 rows][64B] + esq --
__global__ __launch_bounds__(256) void prep_e(const float* __restrict__ cb,
    char* __restrict__ e_prep, float* __restrict__ esq, int* __restrict__ cnts)
{
    __shared__ u16 eh[256];
    __shared__ float red[4];
    int k = blockIdx.x, c = threadIdx.x;
    float v = cb[(size_t)k * CC + c];
    eh[c] = __half_as_ushort(__float2half(v));
    float s = v * v;
    #pragma unroll
    for (int m = 32; m; m >>= 1) s += __shfl_xor(s, m, 64);
    if ((c & 63) == 0) red[c >> 6] = s;
    __syncthreads();
    if (c == 0) {
        esq[k] = (red[0] + red[1]) + (red[2] + red[3]);
        if (k == 0) { cnts[0] = 0; cnts[1] = 0; }
    }
    if (c < 32) {                       // 8 images (ks) x 4 slots (sp)
        int ks = c >> 2, sp = c & 3;
        int pass = k >> 8, row = k & 255;
        int kg = sp ^ ((row ^ (row >> 2)) & 3);
        short8v w;
        #pragma unroll
        for (int j = 0; j < 8; ++j) w[j] = (short)eh[ks * 32 + kg * 8 + j];
        *(short8v*)(e_prep + (size_t)(pass * 8 + ks) * 16384 + row * 64 + sp * 16) = w;
    }
}

// ---------- prep_xT: x NCHW fp32 -> fp16 swizzled chunks (in d_out) ----------
// x_prep: [blk 2048][ks 8][4 KB: row(px)*64 + slot*16], gld-linear-ready.
__global__ __launch_bounds__(256) void prep_xT(const float* __restrict__ x,
    char* __restrict__ x_prep)
{
    __shared__ u32 pk[64 * 261];      // [px][c] fp16 in low bits
    const int blk = blockIdx.x, t = threadIdx.x;
    const float* xb = x + (size_t)(blk >> 6) * (CC * HWIMG) + (blk & 63) * 64;
    #pragma unroll 4
    for (int p = 0; p < 16; ++p) {
        int c = p * 16 + (t >> 4);
        int px4 = (t & 15) * 4;
        float4 v = *(const float4*)&xb[(size_t)c * HWIMG + px4];
        float vv[4] = {v.x, v.y, v.z, v.w};
        #pragma unroll
        for (int i = 0; i < 4; ++i)
            pk[(px4 + i) * 261 + c] = (u32)__half_as_ushort(__float2half(vv[i]));
    }
    __syncthreads();
    char* obase = x_prep + (size_t)blk * 32768;
    #pragma unroll
    for (int i = 0; i < 8; ++i) {
        int gid = t + 256 * i;            // [ks 8][px 64][sp 4]
        int ks = gid >> 8, rem = gid & 255, px = rem >> 2, sp = rem & 3;
        int kg = sp ^ ((px ^ (px >> 2)) & 3);
        const u32* pr = &pk[px * 261 + ks * 32 + kg * 8];
        short8v ov;
        #pragma unroll
        for (int j = 0; j < 8; ++j) ov[j] = (short)(pr[j] & 0xFFFF);
        *(short8v*)(obase + gid * 16) = ov;
    }
}

// ---------- dist: 1-term fp16 MFMA + 2-phase dbuf pipeline + top-2 argmin ----
// 256 thr = 4 waves (code quarters). 32 chunks (pass 0..3 x ks 0..7, BK=32ch).
// LDS: 2 x (x 4 KB | e 16 KB) = 40 KB. Counted vmcnt(5), raw s_barrier.
__global__ __launch_bounds__(256, 3) void dist_kernel(
    const char* __restrict__ x_prep, const char* __restrict__ e_prep,
    const float* __restrict__ esq,
    int* __restrict__ min_idx, int* __restrict__ cnts,
    int* __restrict__ full_list)
{
    __shared__ char smem[40960];

    const int t = threadIdx.x;
    const int l = t & 63;
    const int wid = t >> 6;
    const int n0 = blockIdx.x * 64;

    const int lrow = l & 15;
    const int kg   = l >> 4;
    const int lo   = lrow * 64 + (kg ^ ((lrow ^ (lrow >> 2)) & 3)) * 16;

    const char* xsrc = x_prep + (size_t)blockIdx.x * 32768;

    float min1[16], min2[16]; int idx1[16];
    #pragma unroll
    for (int s = 0; s < 16; ++s) { min1[s] = 3.4e38f; min2[s] = 3.4e38f; idx1[s] = 0; }

    f32x4 acc[4][4];

#define STAGE(cur_, tc_) do {                                                  \
        char* bx_ = smem + (cur_) * 20480;                                     \
        const char* es_ = e_prep + (size_t)(tc_) * 16384;                      \
        gld16(xsrc + ((tc_) & 7) * 4096 + wid * 1024 + l * 16,                 \
              bx_ + wid * 1024);                                               \
        _Pragma("unroll")                                                      \
        for (int i_ = 0; i_ < 4; ++i_)                                         \
            gld16(es_ + i_ * 4096 + wid * 1024 + l * 16,                       \
                  bx_ + 4096 + i_ * 4096 + wid * 1024);                        \
    } while (0)

    STAGE(0, 0);
    STAGE(1, 1);

    for (int tc = 0; tc < 32; ++tc) {
        const int cur = tc & 1;
        if (tc == 31) asm volatile("s_waitcnt vmcnt(0)" ::: "memory");
        else          asm volatile("s_waitcnt vmcnt(5)" ::: "memory");
        __builtin_amdgcn_s_barrier();
        __builtin_amdgcn_sched_barrier(0);

        const char* bx = smem + cur * 20480;
        const char* be = bx + 4096;
        const int ks = tc & 7;

        if (ks == 0) {
            #pragma unroll
            for (int m = 0; m < 4; ++m)
                #pragma unroll
                for (int n = 0; n < 4; ++n) acc[m][n] = (f32x4){0.f, 0.f, 0.f, 0.f};
        }
        half8 B[4], A[4];
        #pragma unroll
        for (int n = 0; n < 4; ++n)
            B[n] = *(const half8*)(be + wid * 4096 + n * 1024 + lo);
        #pragma unroll
        for (int m = 0; m < 4; ++m)
            A[m] = *(const half8*)(bx + m * 1024 + lo);
        #pragma unroll
        for (int m = 0; m < 4; ++m)
            #pragma unroll
            for (int n = 0; n < 4; ++n)
                acc[m][n] = __builtin_amdgcn_mfma_f32_16x16x32_f16(A[m], B[n], acc[m][n], 0, 0, 0);

        if (ks == 7) {   // pass epilogue: d = esq - 2*dot, top-2 update
            const int pass = tc >> 3;
            #pragma unroll
            for (int n = 0; n < 4; ++n) {
                int code = pass * 256 + wid * 64 + n * 16 + lrow;
                float eq = esq[code];
                #pragma unroll
                for (int m = 0; m < 4; ++m) {
                    #pragma unroll
                    for (int q = 0; q < 4; ++q) {
                        float d = fmaf(-2.0f, acc[m][n][q], eq);
                        int s = m * 4 + q;
                        if (d < min1[s]) { min2[s] = min1[s]; min1[s] = d; idx1[s] = code; }
                        else if (d < min2[s]) { min2[s] = d; }
                    }
                }
            }
        }
        __builtin_amdgcn_sched_barrier(0);
        __builtin_amdgcn_s_barrier();
        if (tc < 30) STAGE(cur, tc + 2);
    }
#undef STAGE

    // reduce across 16 code-lanes, then across the 4 waves
    float* rm1 = (float*)smem;
    float* rm2 = (float*)(smem + 1024);
    int*   rim = (int*)(smem + 2048);
    #pragma unroll
    for (int s = 0; s < 16; ++s) {
        float m1 = min1[s]; int i1 = idx1[s]; float m2 = min2[s];
        #pragma unroll
        for (int msk = 1; msk <= 8; msk <<= 1) {
            float o1 = __shfl_xor(m1, msk, 64);
            int   oi = __shfl_xor(i1, msk, 64);
            float o2 = __shfl_xor(m2, msk, 64);
            if (o1 < m1 || (o1 == m1 && oi < i1)) { m2 = fminf(fminf(m2, o2), m1); m1 = o1; i1 = oi; }
            else { m2 = fminf(fminf(m2, o2), o1); }
        }
        if (lrow == 0) {
            int px_local = (s >> 2) * 16 + (l >> 4) * 4 + (s & 3);
            rm1[wid * 64 + px_local] = m1;
            rm2[wid * 64 + px_local] = m2;
            rim[wid * 64 + px_local] = i1;
        }
    }
    __syncthreads();
    if (t < 64) {
        float m1 = rm1[t]; int i1 = rim[t]; float m2 = rm2[t];
        #pragma unroll
        for (int w = 1; w < 4; ++w) {
            float o1 = rm1[w * 64 + t]; int oi = rim[w * 64 + t]; float o2 = rm2[w * 64 + t];
            if (o1 < m1 || (o1 == m1 && oi < i1)) { m2 = fminf(fminf(m2, o2), m1); m1 = o1; i1 = oi; }
            else { m2 = fminf(fminf(m2, o2), o1); }
        }
        int n = n0 + t;
        min_idx[n] = i1;
        if (m2 - m1 <= MARGIN) {
            int slot = atomicAdd(&cnts[0], 1);
            if (slot < FULLCAP) full_list[slot] = n;
        }
    }
}

// ---------- recheck_full4: fp64 exact argmin, 4 flagged pixels per block -----
__global__ __launch_bounds__(256) void recheck_full4(
    const float* __restrict__ x, const float* __restrict__ cb,
    const int* __restrict__ cnts, const int* __restrict__ full_list,
    int* __restrict__ min_idx)
{
    __shared__ float  xs[4][CC];
    __shared__ double rbest[4][256];
    __shared__ int    ribst[4][256];
    int cnt = cnts[0]; if (cnt > FULLCAP) cnt = FULLCAP;
    int ngrp = (cnt + 3) >> 2;
    const int t = threadIdx.x;
    for (int g = blockIdx.x; g < ngrp; g += gridDim.x) {
        int npx = cnt - g * 4; if (npx > 4) npx = 4;
        for (int i = t; i < npx * 256; i += 256) {
            int p = i >> 8, c = i & 255;
            int n = full_list[g * 4 + p];
            int b = n / HWIMG, hw = n % HWIMG;
            xs[p][c] = x[(size_t)b * CC * HWIMG + (size_t)c * HWIMG + hw];
        }
        __syncthreads();
        double best[4] = {1e300, 1e300, 1e300, 1e300};
        int bi[4] = {0, 0, 0, 0};
        #pragma unroll
        for (int kk = 0; kk < 4; ++kk) {
            int k = t * 4 + kk;
            const float4* er = (const float4*)(cb + (size_t)k * CC);
            double s[4] = {0.0, 0.0, 0.0, 0.0};
            for (int c4 = 0; c4 < 64; ++c4) {
                float4 e = er[c4];
                float ea[4] = {e.x, e.y, e.z, e.w};
                #pragma unroll
                for (int j = 0; j < 4; ++j) {
                    #pragma unroll
                    for (int p = 0; p < 4; ++p) {
                        double d = (double)xs[p][c4 * 4 + j] - (double)ea[j];
                        s[p] = fma(d, d, s[p]);
                    }
                }
            }
            #pragma unroll
            for (int p = 0; p < 4; ++p)
                if (s[p] < best[p]) { best[p] = s[p]; bi[p] = k; }
        }
        #pragma unroll
        for (int p = 0; p < 4; ++p) { rbest[p][t] = best[p]; ribst[p][t] = bi[p]; }
        __syncthreads();
        for (int st = 128; st; st >>= 1) {
            if (t < st) {
                #pragma unroll
                for (int p = 0; p < 4; ++p) {
                    double ov = rbest[p][t + st]; int oi = ribst[p][t + st];
                    if (ov < rbest[p][t] || (ov == rbest[p][t] && oi < ribst[p][t])) {
                        rbest[p][t] = ov; ribst[p][t] = oi;
                    }
                }
            }
            __syncthreads();
        }
        if (t < npx) min_idx[full_list[g * 4 + t]] = ribst[t][0];
        __syncthreads();
    }
}

// ---------- out: gather quantized (NCHW) + fp64 loss partials ----------------
__global__ __launch_bounds__(256) void out_kernel(
    const float* __restrict__ x, const float* __restrict__ cb,
    const int* __restrict__ min_idx, float* __restrict__ out,
    double* __restrict__ partials)
{
    int n = blockIdx.x * 256 + threadIdx.x;
    int b = n / HWIMG, hw = n % HWIMG;
    const float* xb = x + (size_t)b * CC * HWIMG + hw;
    float*       ob = out + (size_t)b * CC * HWIMG + hw;
    int k = min_idx[n];
    const float* er = cb + (size_t)k * CC;
    double ls = 0.0;
    #pragma unroll 4
    for (int c = 0; c < CC; c += 4) {
        float4 q = *(const float4*)&er[c];
        float x0 = xb[(size_t)(c + 0) * HWIMG];
        float x1 = xb[(size_t)(c + 1) * HWIMG];
        float x2 = xb[(size_t)(c + 2) * HWIMG];
        float x3 = xb[(size_t)(c + 3) * HWIMG];
        ob[(size_t)(c + 0) * HWIMG] = q.x;
        ob[(size_t)(c + 1) * HWIMG] = q.y;
        ob[(size_t)(c + 2) * HWIMG] = q.z;
        ob[(size_t)(c + 3) * HWIMG] = q.w;
        double d0 = (double)q.x - (double)x0;
        double d1 = (double)q.y - (double)x1;
        double d2 = (double)q.z - (double)x2;
        double d3 = (double)q.w - (double)x3;
        ls += d0 * d0 + d1 * d1 + d2 * d2 + d3 * d3;
    }
    __shared__ double sred[256];
    sred[threadIdx.x] = ls;
    __syncthreads();
    for (int s = 128; s; s >>= 1) {
        if (threadIdx.x < (unsigned)s) sred[threadIdx.x] += sred[threadIdx.x + s];
        __syncthreads();
    }
    if (threadIdx.x == 0) partials[blockIdx.x] = sred[0];
}

__global__ void loss_kernel(const double* __restrict__ partials, float* __restrict__ out)
{
    if (threadIdx.x == 0 && blockIdx.x == 0) {
        double s = 0.0;
        for (int i = 0; i < 512; i++) s += partials[i];
        out[33554432] = (float)(1.25 * s / 33554432.0);
    }
}

// ---------- launch -----------------------------------------------------------
extern "C" void kernel_launch(void* const* d_in, const int* in_sizes, int n_in,
                              void* d_out, int out_size, void* d_ws, size_t ws_size,
                              hipStream_t stream)
{
    const float* x  = (const float*)d_in[0];
    const float* cb = (const float*)d_in[1];
    float* out = (float*)d_out;

    // x_prep (64 MB) lives in d_out; out_kernel rewrites d_out afterwards.
    char* x_prep = (char*)d_out;

    char* ws = (char*)d_ws;
    char*   e_prep    = (char*) (ws + 0);            //   524,288 B
    float*  esq       = (float*)(ws + 524288);       //     4,096 B
    int*    min_idx   = (int*)  (ws + 528384);       //   524,288 B
    int*    cnts      = (int*)  (ws + 1052672);      //        16 B
    int*    full_list = (int*)  (ws + 1052688);      //   131,072 B
    double* partials  = (double*)(ws + 1183760);     //     4,096 B

    prep_e       <<<KCODES, 256, 0, stream>>>(cb, e_prep, esq, cnts);
    prep_xT      <<<NPIX / 64, 256, 0, stream>>>(x, x_prep);
    dist_kernel  <<<NPIX / 64, 256, 0, stream>>>(x_prep, e_prep, esq,
                                                 min_idx, cnts, full_list);
    recheck_full4<<<1024, 256, 0, stream>>>(x, cb, cnts, full_list, min_idx);
    out_kernel   <<<NPIX / 256, 256, 0, stream>>>(x, cb, min_idx, out, partials);
    loss_kernel  <<<1, 64, 0, stream>>>(partials, out);
}